// Round 1
// baseline (2406.747 us; speedup 1.0000x reference)
//
#include <hip/hip_runtime.h>
#include <hip/hip_bf16.h>

#define DD 96

// Detect whether the edge-index buffer is int64 or int32.
// Interpreting int32 random data in [0,50000) as int64 gives huge values
// (hi word nonzero) almost surely; true int64 indices are all < N.
__global__ void detect_idx_kernel(const unsigned long long* __restrict__ idx,
                                  int* __restrict__ flag,
                                  unsigned long long nmax) {
    __shared__ int bad;
    if (threadIdx.x == 0) bad = 0;
    __syncthreads();
    unsigned long long v = idx[threadIdx.x];
    if (v >= nmax) bad = 1;  // benign race: any writer sets 1
    __syncthreads();
    if (threadIdx.x == 0) *flag = bad ? 0 : 1;  // 1 => int64 layout
}

// agg[dst] += feat[src], one thread per (edge, 4-float chunk).
__global__ __launch_bounds__(256) void scatter_add_kernel(
    const float* __restrict__ feat, const void* __restrict__ eidx,
    const int* __restrict__ flag, float* __restrict__ agg,
    int E, int n) {
    long long t = (long long)blockIdx.x * 256 + threadIdx.x;
    if (t >= (long long)E * 24) return;
    int e = (int)(t / 24);
    int c = (int)(t % 24);
    int s, d;
    if (*flag) {
        const long long* p = (const long long*)eidx;
        s = (int)p[e];
        d = (int)p[E + e];
    } else {
        const int* p = (const int*)eidx;
        s = p[e];
        d = p[E + e];
    }
    if ((unsigned)s >= (unsigned)n || (unsigned)d >= (unsigned)n) return;
    const float4 v = ((const float4*)(feat + (size_t)s * DD))[c];
    float* o = agg + (size_t)d * DD + (size_t)c * 4;
    atomicAdd(o + 0, v.x);
    atomicAdd(o + 1, v.y);
    atomicAdd(o + 2, v.z);
    atomicAdd(o + 3, v.w);
}

// out[i] = (relu?) agg[i] @ Wrel + bias + X[i] @ Wroot
// Block = 256 threads = 64 nodes x 4 output-quarters (24 outputs each).
// Wave-uniform quarter => weight loads are wave-uniform => scalar K$ loads.
// X may alias out (layer 2): all readers/writers of row i are in one block,
// so a __syncthreads() between the k-loop and the store makes it safe.
__global__ __launch_bounds__(256) void linear_kernel(
    const float* __restrict__ A, const float* __restrict__ X,
    const float* __restrict__ Wrel, const float* __restrict__ bias,
    const float* __restrict__ Wroot, float* __restrict__ out,
    int n, int do_relu) {
    const int lane = threadIdx.x & 63;
    const int quarter = threadIdx.x >> 6;  // 0..3, uniform per wave
    const int node = blockIdx.x * 64 + lane;
    const int j0 = quarter * 24;

    float acc[24];
    bool active = (node < n);

    if (active) {
        #pragma unroll
        for (int j = 0; j < 24; ++j) acc[j] = bias[j0 + j];

        const float* arow = A + (size_t)node * DD;
        const float* xrow = X + (size_t)node * DD;

        for (int kk = 0; kk < DD; kk += 4) {
            float4 av4 = *(const float4*)(arow + kk);
            float4 xv4 = *(const float4*)(xrow + kk);
            const float av[4] = {av4.x, av4.y, av4.z, av4.w};
            const float xv[4] = {xv4.x, xv4.y, xv4.z, xv4.w};
            #pragma unroll
            for (int u = 0; u < 4; ++u) {
                const float* wr = Wrel + (size_t)(kk + u) * DD + j0;
                const float* wo = Wroot + (size_t)(kk + u) * DD + j0;
                #pragma unroll
                for (int j = 0; j < 24; ++j)
                    acc[j] = fmaf(av[u], wr[j], fmaf(xv[u], wo[j], acc[j]));
            }
        }
    }

    __syncthreads();  // X may alias out: finish all reads before any store

    if (active) {
        float* orow = out + (size_t)node * DD + j0;
        #pragma unroll
        for (int j = 0; j < 24; ++j) {
            float v = acc[j];
            if (do_relu) v = fmaxf(v, 0.f);
            orow[j] = v;
        }
    }
}

extern "C" void kernel_launch(void* const* d_in, const int* in_sizes, int n_in,
                              void* d_out, int out_size, void* d_ws, size_t ws_size,
                              hipStream_t stream) {
    const float* x      = (const float*)d_in[0];
    const void*  eidx   = d_in[1];
    const float* W1_rel = (const float*)d_in[2];
    const float* b1     = (const float*)d_in[3];
    const float* W1_root= (const float*)d_in[4];
    const float* W2_rel = (const float*)d_in[5];
    const float* b2     = (const float*)d_in[6];
    const float* W2_root= (const float*)d_in[7];
    float* out = (float*)d_out;

    const int N = in_sizes[0] / DD;   // 50000
    const int E = in_sizes[1] / 2;    // 800000

    float* agg = (float*)d_ws;                                   // N*96 floats
    int*   flag = (int*)((char*)d_ws + (size_t)N * DD * sizeof(float));

    const size_t agg_bytes = (size_t)N * DD * sizeof(float);
    const long long scatter_threads = (long long)E * 24;
    const int scatter_blocks = (int)((scatter_threads + 255) / 256);
    const int linear_blocks = (N + 63) / 64;

    detect_idx_kernel<<<1, 256, 0, stream>>>(
        (const unsigned long long*)eidx, flag, (unsigned long long)N);

    // Layer 1
    hipMemsetAsync(agg, 0, agg_bytes, stream);
    scatter_add_kernel<<<scatter_blocks, 256, 0, stream>>>(x, eidx, flag, agg, E, N);
    linear_kernel<<<linear_blocks, 256, 0, stream>>>(agg, x, W1_rel, b1, W1_root,
                                                     out, N, 1);  // h -> d_out

    // Layer 2 (h lives in d_out; linear_kernel handles the aliasing)
    hipMemsetAsync(agg, 0, agg_bytes, stream);
    scatter_add_kernel<<<scatter_blocks, 256, 0, stream>>>(out, eidx, flag, agg, E, N);
    linear_kernel<<<linear_blocks, 256, 0, stream>>>(agg, out, W2_rel, b2, W2_root,
                                                     out, N, 0);
}

// Round 2
// 597.202 us; speedup vs baseline: 4.0300x; 4.0300x over previous
//
#include <hip/hip_runtime.h>
#include <hip/hip_bf16.h>

#define DD 96

// ---------------- dtype detect ----------------
// Interpreting int32 random data in [0,50000) as int64 gives hi-word != 0
// almost surely; true int64 indices are all < N.
__global__ void detect_idx_kernel(const unsigned long long* __restrict__ idx,
                                  int* __restrict__ flag,
                                  unsigned long long nmax) {
    __shared__ int bad;
    if (threadIdx.x == 0) bad = 0;
    __syncthreads();
    unsigned long long v = idx[threadIdx.x];
    if (v >= nmax) bad = 1;
    __syncthreads();
    if (threadIdx.x == 0) *flag = bad ? 0 : 1;  // 1 => int64 layout
}

__device__ __forceinline__ int load_idx(const void* eidx, int isI64, int pos) {
    return isI64 ? (int)((const long long*)eidx)[pos] : ((const int*)eidx)[pos];
}

// ---------------- CSR build ----------------
__global__ __launch_bounds__(256) void hist_kernel(
    const void* __restrict__ eidx, const int* __restrict__ flag,
    int* __restrict__ deg, int E, int n) {
    int e = blockIdx.x * 256 + threadIdx.x;
    if (e >= E) return;
    int d = load_idx(eidx, *flag, E + e);
    if ((unsigned)d < (unsigned)n) atomicAdd(&deg[d], 1);
}

#define SCAN_BLOCK 256
#define SCAN_ELEMS 1024

// per-1024-chunk exclusive scan + chunk totals
__global__ __launch_bounds__(SCAN_BLOCK) void scan1_kernel(
    const int* __restrict__ deg, int* __restrict__ partial,
    int* __restrict__ blockSums, int n) {
    __shared__ int sh[SCAN_BLOCK];
    int base = blockIdx.x * SCAN_ELEMS;
    int vals[4];
    int tsum = 0;
    #pragma unroll
    for (int u = 0; u < 4; ++u) {
        int idx = base + threadIdx.x * 4 + u;
        vals[u] = (idx < n) ? deg[idx] : 0;
        tsum += vals[u];
    }
    sh[threadIdx.x] = tsum;
    __syncthreads();
    int v = tsum;
    for (int off = 1; off < SCAN_BLOCK; off <<= 1) {
        int o = (threadIdx.x >= off) ? sh[threadIdx.x - off] : 0;
        __syncthreads();
        v += o;
        sh[threadIdx.x] = v;
        __syncthreads();
    }
    int run = v - tsum;  // exclusive prefix of this thread's 4-group
    #pragma unroll
    for (int u = 0; u < 4; ++u) {
        int idx = base + threadIdx.x * 4 + u;
        if (idx < n) partial[idx] = run;
        run += vals[u];
    }
    if (threadIdx.x == SCAN_BLOCK - 1) blockSums[blockIdx.x] = v;
}

// scan the (<=256) chunk totals in one block -> exclusive
__global__ __launch_bounds__(256) void scan2_kernel(int* __restrict__ blockSums, int nb) {
    __shared__ int sh[256];
    int v = (threadIdx.x < nb) ? blockSums[threadIdx.x] : 0;
    sh[threadIdx.x] = v;
    __syncthreads();
    int inc = v;
    for (int off = 1; off < 256; off <<= 1) {
        int o = (threadIdx.x >= off) ? sh[threadIdx.x - off] : 0;
        __syncthreads();
        inc += o;
        sh[threadIdx.x] = inc;
        __syncthreads();
    }
    if (threadIdx.x < nb) blockSums[threadIdx.x] = inc - v;
}

__global__ __launch_bounds__(256) void scan3_kernel(
    const int* __restrict__ partial, const int* __restrict__ blockSums,
    int* __restrict__ offsets, int* __restrict__ cursor, int n, int E) {
    int i = blockIdx.x * 256 + threadIdx.x;
    if (i < n) {
        int o = partial[i] + blockSums[i >> 10];
        offsets[i] = o;
        cursor[i] = o;
    }
    if (i == n) offsets[n] = E;
}

__global__ __launch_bounds__(256) void bucket_kernel(
    const void* __restrict__ eidx, const int* __restrict__ flag,
    int* __restrict__ cursor, int* __restrict__ ssrc, int E, int n) {
    int e = blockIdx.x * 256 + threadIdx.x;
    if (e >= E) return;
    int isI64 = *flag;
    int s = load_idx(eidx, isI64, e);
    int d = load_idx(eidx, isI64, E + e);
    if ((unsigned)s >= (unsigned)n || (unsigned)d >= (unsigned)n) return;
    int pos = atomicAdd(&cursor[d], 1);
    ssrc[pos] = s;
}

// ---------------- gather aggregation (no atomics) ----------------
// thread = (node i, float4-chunk c in [0,24)); sums x[src] rows over in-edges.
__global__ __launch_bounds__(256) void gather_agg_kernel(
    const float* __restrict__ feat, const int* __restrict__ offsets,
    const int* __restrict__ ssrc, float* __restrict__ agg, int n) {
    long long t = (long long)blockIdx.x * 256 + threadIdx.x;
    if (t >= (long long)n * 24) return;
    int i = (int)(t / 24);
    int c = (int)(t % 24);
    int beg = offsets[i], end = offsets[i + 1];
    float4 acc = make_float4(0.f, 0.f, 0.f, 0.f);
    for (int j = beg; j < end; ++j) {
        int s = ssrc[j];
        float4 v = ((const float4*)(feat + (size_t)s * DD))[c];
        acc.x += v.x; acc.y += v.y; acc.z += v.z; acc.w += v.w;
    }
    ((float4*)(agg + (size_t)i * DD))[c] = acc;
}

// ---------------- fallback: atomic scatter (baseline) ----------------
__global__ __launch_bounds__(256) void scatter_add_kernel(
    const float* __restrict__ feat, const void* __restrict__ eidx,
    const int* __restrict__ flag, float* __restrict__ agg,
    int E, int n) {
    long long t = (long long)blockIdx.x * 256 + threadIdx.x;
    if (t >= (long long)E * 24) return;
    int e = (int)(t / 24);
    int c = (int)(t % 24);
    int isI64 = *flag;
    int s = load_idx(eidx, isI64, e);
    int d = load_idx(eidx, isI64, E + e);
    if ((unsigned)s >= (unsigned)n || (unsigned)d >= (unsigned)n) return;
    const float4 v = ((const float4*)(feat + (size_t)s * DD))[c];
    float* o = agg + (size_t)d * DD + (size_t)c * 4;
    atomicAdd(o + 0, v.x);
    atomicAdd(o + 1, v.y);
    atomicAdd(o + 2, v.z);
    atomicAdd(o + 3, v.w);
}

// ---------------- fused dual-linear ----------------
// out[i] = (relu?)(agg[i] @ Wrel + bias + X[i] @ Wroot)
// Block = 64 nodes x 4 output-quarters; weight reads wave-uniform (K$).
// X may alias out (layer 2): __syncthreads() between reads and stores, all
// readers/writers of a row live in one block.
__global__ __launch_bounds__(256) void linear_kernel(
    const float* __restrict__ A, const float* __restrict__ X,
    const float* __restrict__ Wrel, const float* __restrict__ bias,
    const float* __restrict__ Wroot, float* __restrict__ out,
    int n, int do_relu) {
    const int lane = threadIdx.x & 63;
    const int quarter = threadIdx.x >> 6;
    const int node = blockIdx.x * 64 + lane;
    const int j0 = quarter * 24;

    float acc[24];
    bool active = (node < n);

    if (active) {
        #pragma unroll
        for (int j = 0; j < 24; ++j) acc[j] = bias[j0 + j];

        const float* arow = A + (size_t)node * DD;
        const float* xrow = X + (size_t)node * DD;

        for (int kk = 0; kk < DD; kk += 4) {
            float4 av4 = *(const float4*)(arow + kk);
            float4 xv4 = *(const float4*)(xrow + kk);
            const float av[4] = {av4.x, av4.y, av4.z, av4.w};
            const float xv[4] = {xv4.x, xv4.y, xv4.z, xv4.w};
            #pragma unroll
            for (int u = 0; u < 4; ++u) {
                const float* wr = Wrel + (size_t)(kk + u) * DD + j0;
                const float* wo = Wroot + (size_t)(kk + u) * DD + j0;
                #pragma unroll
                for (int j = 0; j < 24; ++j)
                    acc[j] = fmaf(av[u], wr[j], fmaf(xv[u], wo[j], acc[j]));
            }
        }
    }

    __syncthreads();

    if (active) {
        float* orow = out + (size_t)node * DD + j0;
        #pragma unroll
        for (int j = 0; j < 24; ++j) {
            float v = acc[j];
            if (do_relu) v = fmaxf(v, 0.f);
            orow[j] = v;
        }
    }
}

extern "C" void kernel_launch(void* const* d_in, const int* in_sizes, int n_in,
                              void* d_out, int out_size, void* d_ws, size_t ws_size,
                              hipStream_t stream) {
    const float* x      = (const float*)d_in[0];
    const void*  eidx   = d_in[1];
    const float* W1_rel = (const float*)d_in[2];
    const float* b1     = (const float*)d_in[3];
    const float* W1_root= (const float*)d_in[4];
    const float* W2_rel = (const float*)d_in[5];
    const float* b2     = (const float*)d_in[6];
    const float* W2_root= (const float*)d_in[7];
    float* out = (float*)d_out;

    const int N = in_sizes[0] / DD;   // 50000
    const int E = in_sizes[1] / 2;    // 800000

    // ws layout (fallback prefix identical to passing baseline):
    //   [0)                 agg      : N*96 floats
    //   [aggB)              flag     : 1 int
    //   [aggB+16, aligned)  offsets  : N+1 ints
    //                       cursor   : N ints
    //                       deg      : N ints
    //                       partial  : N ints
    //                       blockSums: 256 ints
    //                       ssrc     : E ints
    const size_t aggB = (size_t)N * DD * sizeof(float);
    char* base = (char*)d_ws;
    float* agg  = (float*)base;
    int*   flag = (int*)(base + aggB);
    size_t off = (aggB + 15) & ~(size_t)15;
    off += 16;
    int* offsets   = (int*)(base + off); off += (size_t)(N + 1) * 4;
    int* cursor    = (int*)(base + off); off += (size_t)N * 4;
    int* deg       = (int*)(base + off); off += (size_t)N * 4;
    int* partial   = (int*)(base + off); off += (size_t)N * 4;
    int* blockSums = (int*)(base + off); off += 256 * 4;
    int* ssrc      = (int*)(base + off); off += (size_t)E * 4;
    const bool csr_ok = (off <= ws_size) && (N <= SCAN_ELEMS * 256);

    const int linear_blocks = (N + 63) / 64;
    const int edge_blocks = (E + 255) / 256;

    detect_idx_kernel<<<1, 256, 0, stream>>>(
        (const unsigned long long*)eidx, flag, (unsigned long long)N);

    if (csr_ok) {
        const int NB = (N + SCAN_ELEMS - 1) / SCAN_ELEMS;
        const int gather_blocks = (int)(((long long)N * 24 + 255) / 256);

        // CSR build (once, reused by both layers)
        hipMemsetAsync(deg, 0, (size_t)N * 4, stream);
        hist_kernel<<<edge_blocks, 256, 0, stream>>>(eidx, flag, deg, E, N);
        scan1_kernel<<<NB, SCAN_BLOCK, 0, stream>>>(deg, partial, blockSums, N);
        scan2_kernel<<<1, 256, 0, stream>>>(blockSums, NB);
        scan3_kernel<<<(N + 256) / 256, 256, 0, stream>>>(partial, blockSums,
                                                          offsets, cursor, N, E);
        bucket_kernel<<<edge_blocks, 256, 0, stream>>>(eidx, flag, cursor, ssrc, E, N);

        // Layer 1
        gather_agg_kernel<<<gather_blocks, 256, 0, stream>>>(x, offsets, ssrc, agg, N);
        linear_kernel<<<linear_blocks, 256, 0, stream>>>(agg, x, W1_rel, b1, W1_root,
                                                         out, N, 1);
        // Layer 2 (h in d_out)
        gather_agg_kernel<<<gather_blocks, 256, 0, stream>>>(out, offsets, ssrc, agg, N);
        linear_kernel<<<linear_blocks, 256, 0, stream>>>(agg, out, W2_rel, b2, W2_root,
                                                         out, N, 0);
    } else {
        const int scatter_blocks = (int)(((long long)E * 24 + 255) / 256);
        hipMemsetAsync(agg, 0, aggB, stream);
        scatter_add_kernel<<<scatter_blocks, 256, 0, stream>>>(x, eidx, flag, agg, E, N);
        linear_kernel<<<linear_blocks, 256, 0, stream>>>(agg, x, W1_rel, b1, W1_root,
                                                         out, N, 1);
        hipMemsetAsync(agg, 0, aggB, stream);
        scatter_add_kernel<<<scatter_blocks, 256, 0, stream>>>(out, eidx, flag, agg, E, N);
        linear_kernel<<<linear_blocks, 256, 0, stream>>>(agg, out, W2_rel, b2, W2_root,
                                                         out, N, 0);
    }
}

// Round 3
// 369.073 us; speedup vs baseline: 6.5211x; 1.6181x over previous
//
#include <hip/hip_runtime.h>
#include <hip/hip_bf16.h>

#define DD 96

// ---------------- dtype detect ----------------
__global__ void detect_idx_kernel(const unsigned long long* __restrict__ idx,
                                  int* __restrict__ flag,
                                  unsigned long long nmax) {
    __shared__ int bad;
    if (threadIdx.x == 0) bad = 0;
    __syncthreads();
    unsigned long long v = idx[threadIdx.x];
    if (v >= nmax) bad = 1;
    __syncthreads();
    if (threadIdx.x == 0) *flag = bad ? 0 : 1;  // 1 => int64 layout
}

__device__ __forceinline__ int load_idx(const void* eidx, int isI64, int pos) {
    return isI64 ? (int)((const long long*)eidx)[pos] : ((const int*)eidx)[pos];
}

// ---------------- CSR build ----------------
__global__ __launch_bounds__(256) void hist_kernel(
    const void* __restrict__ eidx, const int* __restrict__ flag,
    int* __restrict__ deg, int E, int n) {
    int e = blockIdx.x * 256 + threadIdx.x;
    if (e >= E) return;
    int d = load_idx(eidx, *flag, E + e);
    if ((unsigned)d < (unsigned)n) atomicAdd(&deg[d], 1);
}

#define SCAN_BLOCK 256
#define SCAN_ELEMS 1024

__global__ __launch_bounds__(SCAN_BLOCK) void scan1_kernel(
    const int* __restrict__ deg, int* __restrict__ partial,
    int* __restrict__ blockSums, int n) {
    __shared__ int sh[SCAN_BLOCK];
    int base = blockIdx.x * SCAN_ELEMS;
    int vals[4];
    int tsum = 0;
    #pragma unroll
    for (int u = 0; u < 4; ++u) {
        int idx = base + threadIdx.x * 4 + u;
        vals[u] = (idx < n) ? deg[idx] : 0;
        tsum += vals[u];
    }
    sh[threadIdx.x] = tsum;
    __syncthreads();
    int v = tsum;
    for (int off = 1; off < SCAN_BLOCK; off <<= 1) {
        int o = (threadIdx.x >= off) ? sh[threadIdx.x - off] : 0;
        __syncthreads();
        v += o;
        sh[threadIdx.x] = v;
        __syncthreads();
    }
    int run = v - tsum;
    #pragma unroll
    for (int u = 0; u < 4; ++u) {
        int idx = base + threadIdx.x * 4 + u;
        if (idx < n) partial[idx] = run;
        run += vals[u];
    }
    if (threadIdx.x == SCAN_BLOCK - 1) blockSums[blockIdx.x] = v;
}

__global__ __launch_bounds__(256) void scan2_kernel(int* __restrict__ blockSums, int nb) {
    __shared__ int sh[256];
    int v = (threadIdx.x < nb) ? blockSums[threadIdx.x] : 0;
    sh[threadIdx.x] = v;
    __syncthreads();
    int inc = v;
    for (int off = 1; off < 256; off <<= 1) {
        int o = (threadIdx.x >= off) ? sh[threadIdx.x - off] : 0;
        __syncthreads();
        inc += o;
        sh[threadIdx.x] = inc;
        __syncthreads();
    }
    if (threadIdx.x < nb) blockSums[threadIdx.x] = inc - v;
}

__global__ __launch_bounds__(256) void scan3_kernel(
    const int* __restrict__ partial, const int* __restrict__ blockSums,
    int* __restrict__ offsets, int* __restrict__ cursor, int n, int E) {
    int i = blockIdx.x * 256 + threadIdx.x;
    if (i < n) {
        int o = partial[i] + blockSums[i >> 10];
        offsets[i] = o;
        cursor[i] = o;
    }
    if (i == n) offsets[n] = E;
}

__global__ __launch_bounds__(256) void bucket_kernel(
    const void* __restrict__ eidx, const int* __restrict__ flag,
    int* __restrict__ cursor, int* __restrict__ ssrc, int E, int n) {
    int e = blockIdx.x * 256 + threadIdx.x;
    if (e >= E) return;
    int isI64 = *flag;
    int s = load_idx(eidx, isI64, e);
    int d = load_idx(eidx, isI64, E + e);
    if ((unsigned)s >= (unsigned)n || (unsigned)d >= (unsigned)n) return;
    int pos = atomicAdd(&cursor[d], 1);
    ssrc[pos] = s;
}

// ---------------- gather aggregation (no atomics) ----------------
__global__ __launch_bounds__(256) void gather_agg_kernel(
    const float* __restrict__ feat, const int* __restrict__ offsets,
    const int* __restrict__ ssrc, float* __restrict__ agg, int n) {
    long long t = (long long)blockIdx.x * 256 + threadIdx.x;
    if (t >= (long long)n * 24) return;
    int i = (int)(t / 24);
    int c = (int)(t % 24);
    int beg = offsets[i], end = offsets[i + 1];
    float4 acc = make_float4(0.f, 0.f, 0.f, 0.f);
    for (int j = beg; j < end; ++j) {
        int s = ssrc[j];
        float4 v = ((const float4*)(feat + (size_t)s * DD))[c];
        acc.x += v.x; acc.y += v.y; acc.z += v.z; acc.w += v.w;
    }
    ((float4*)(agg + (size_t)i * DD))[c] = acc;
}

// ---------------- fallback: atomic scatter ----------------
__global__ __launch_bounds__(256) void scatter_add_kernel(
    const float* __restrict__ feat, const void* __restrict__ eidx,
    const int* __restrict__ flag, float* __restrict__ agg,
    int E, int n) {
    long long t = (long long)blockIdx.x * 256 + threadIdx.x;
    if (t >= (long long)E * 24) return;
    int e = (int)(t / 24);
    int c = (int)(t % 24);
    int isI64 = *flag;
    int s = load_idx(eidx, isI64, e);
    int d = load_idx(eidx, isI64, E + e);
    if ((unsigned)s >= (unsigned)n || (unsigned)d >= (unsigned)n) return;
    const float4 v = ((const float4*)(feat + (size_t)s * DD))[c];
    float* o = agg + (size_t)d * DD + (size_t)c * 4;
    atomicAdd(o + 0, v.x);
    atomicAdd(o + 1, v.y);
    atomicAdd(o + 2, v.z);
    atomicAdd(o + 3, v.w);
}

// ---------------- fused dual-linear, LDS-staged weights ----------------
// out[i] = (relu?)(agg[i] @ Wrel + bias + X[i] @ Wroot)
// Block = 256 threads = 64 lanes x 4 col-quarters; 128 nodes/block, 2/thread.
// Weights staged in LDS (36 KB), read via wave-uniform broadcast ds_read_b128.
// Two phases: W_rel over A rows, then W_root over X rows.
// X may alias out (layer 2): block touches only its own 128 rows; barrier
// before stores.
__global__ __launch_bounds__(256) void linear_kernel(
    const float* __restrict__ A, const float* __restrict__ X,
    const float* __restrict__ Wrel, const float* __restrict__ bias,
    const float* __restrict__ Wroot, float* __restrict__ out,
    int n, int do_relu) {
    __shared__ float wlds[DD * DD];  // 36864 B

    const int lane = threadIdx.x & 63;
    const int q = threadIdx.x >> 6;       // 0..3 (wave-uniform)
    const int j0 = q * 24;
    const int m0 = blockIdx.x * 128 + lane;
    const int m1 = m0 + 64;
    const bool act0 = (m0 < n), act1 = (m1 < n);
    const int r0 = act0 ? m0 : 0;         // clamp reads, guard stores
    const int r1 = act1 ? m1 : 0;

    float acc0[24], acc1[24];
    {
        const float4* bq = (const float4*)(bias + j0);
        #pragma unroll
        for (int jj = 0; jj < 6; ++jj) {
            float4 b = bq[jj];
            acc0[jj*4+0] = b.x; acc0[jj*4+1] = b.y;
            acc0[jj*4+2] = b.z; acc0[jj*4+3] = b.w;
            acc1[jj*4+0] = b.x; acc1[jj*4+1] = b.y;
            acc1[jj*4+2] = b.z; acc1[jj*4+3] = b.w;
        }
    }

    const float* srcs[2] = {A, X};
    const float* mats[2] = {Wrel, Wroot};

    for (int phase = 0; phase < 2; ++phase) {
        // stage weight matrix: 2304 float4, 9 per thread, coalesced
        {
            const float4* wg = (const float4*)mats[phase];
            float4* wl = (float4*)wlds;
            #pragma unroll
            for (int i = 0; i < 9; ++i)
                wl[threadIdx.x + i * 256] = wg[threadIdx.x + i * 256];
        }
        __syncthreads();

        const float* row0 = srcs[phase] + (size_t)r0 * DD;
        const float* row1 = srcs[phase] + (size_t)r1 * DD;

        for (int kk = 0; kk < DD; kk += 4) {
            float4 a0 = *(const float4*)(row0 + kk);
            float4 a1 = *(const float4*)(row1 + kk);
            const float av0[4] = {a0.x, a0.y, a0.z, a0.w};
            const float av1[4] = {a1.x, a1.y, a1.z, a1.w};
            #pragma unroll
            for (int u = 0; u < 4; ++u) {
                const float4* wrow = (const float4*)(&wlds[(kk + u) * DD + j0]);
                const float k0 = av0[u], k1 = av1[u];
                #pragma unroll
                for (int jj = 0; jj < 6; ++jj) {
                    float4 w = wrow[jj];
                    acc0[jj*4+0] = fmaf(k0, w.x, acc0[jj*4+0]);
                    acc0[jj*4+1] = fmaf(k0, w.y, acc0[jj*4+1]);
                    acc0[jj*4+2] = fmaf(k0, w.z, acc0[jj*4+2]);
                    acc0[jj*4+3] = fmaf(k0, w.w, acc0[jj*4+3]);
                    acc1[jj*4+0] = fmaf(k1, w.x, acc1[jj*4+0]);
                    acc1[jj*4+1] = fmaf(k1, w.y, acc1[jj*4+1]);
                    acc1[jj*4+2] = fmaf(k1, w.z, acc1[jj*4+2]);
                    acc1[jj*4+3] = fmaf(k1, w.w, acc1[jj*4+3]);
                }
            }
        }
        __syncthreads();  // wlds reuse (phase 0->1) & alias safety (end)
    }

    // stores (X may alias out; all reads completed before the last barrier)
    if (act0) {
        float4* o = (float4*)(out + (size_t)m0 * DD + j0);
        #pragma unroll
        for (int jj = 0; jj < 6; ++jj) {
            float4 v = make_float4(acc0[jj*4+0], acc0[jj*4+1],
                                   acc0[jj*4+2], acc0[jj*4+3]);
            if (do_relu) {
                v.x = fmaxf(v.x, 0.f); v.y = fmaxf(v.y, 0.f);
                v.z = fmaxf(v.z, 0.f); v.w = fmaxf(v.w, 0.f);
            }
            o[jj] = v;
        }
    }
    if (act1) {
        float4* o = (float4*)(out + (size_t)m1 * DD + j0);
        #pragma unroll
        for (int jj = 0; jj < 6; ++jj) {
            float4 v = make_float4(acc1[jj*4+0], acc1[jj*4+1],
                                   acc1[jj*4+2], acc1[jj*4+3]);
            if (do_relu) {
                v.x = fmaxf(v.x, 0.f); v.y = fmaxf(v.y, 0.f);
                v.z = fmaxf(v.z, 0.f); v.w = fmaxf(v.w, 0.f);
            }
            o[jj] = v;
        }
    }
}

extern "C" void kernel_launch(void* const* d_in, const int* in_sizes, int n_in,
                              void* d_out, int out_size, void* d_ws, size_t ws_size,
                              hipStream_t stream) {
    const float* x      = (const float*)d_in[0];
    const void*  eidx   = d_in[1];
    const float* W1_rel = (const float*)d_in[2];
    const float* b1     = (const float*)d_in[3];
    const float* W1_root= (const float*)d_in[4];
    const float* W2_rel = (const float*)d_in[5];
    const float* b2     = (const float*)d_in[6];
    const float* W2_root= (const float*)d_in[7];
    float* out = (float*)d_out;

    const int N = in_sizes[0] / DD;   // 50000
    const int E = in_sizes[1] / 2;    // 800000

    const size_t aggB = (size_t)N * DD * sizeof(float);
    char* base = (char*)d_ws;
    float* agg  = (float*)base;
    int*   flag = (int*)(base + aggB);
    size_t off = (aggB + 15) & ~(size_t)15;
    off += 16;
    int* offsets   = (int*)(base + off); off += (size_t)(N + 1) * 4;
    int* cursor    = (int*)(base + off); off += (size_t)N * 4;
    int* deg       = (int*)(base + off); off += (size_t)N * 4;
    int* partial   = (int*)(base + off); off += (size_t)N * 4;
    int* blockSums = (int*)(base + off); off += 256 * 4;
    int* ssrc      = (int*)(base + off); off += (size_t)E * 4;
    const bool csr_ok = (off <= ws_size) && (N <= SCAN_ELEMS * 256);

    const int linear_blocks = (N + 127) / 128;
    const int edge_blocks = (E + 255) / 256;

    detect_idx_kernel<<<1, 256, 0, stream>>>(
        (const unsigned long long*)eidx, flag, (unsigned long long)N);

    if (csr_ok) {
        const int NB = (N + SCAN_ELEMS - 1) / SCAN_ELEMS;
        const int gather_blocks = (int)(((long long)N * 24 + 255) / 256);

        hipMemsetAsync(deg, 0, (size_t)N * 4, stream);
        hist_kernel<<<edge_blocks, 256, 0, stream>>>(eidx, flag, deg, E, N);
        scan1_kernel<<<NB, SCAN_BLOCK, 0, stream>>>(deg, partial, blockSums, N);
        scan2_kernel<<<1, 256, 0, stream>>>(blockSums, NB);
        scan3_kernel<<<(N + 256) / 256, 256, 0, stream>>>(partial, blockSums,
                                                          offsets, cursor, N, E);
        bucket_kernel<<<edge_blocks, 256, 0, stream>>>(eidx, flag, cursor, ssrc, E, N);

        gather_agg_kernel<<<gather_blocks, 256, 0, stream>>>(x, offsets, ssrc, agg, N);
        linear_kernel<<<linear_blocks, 256, 0, stream>>>(agg, x, W1_rel, b1, W1_root,
                                                         out, N, 1);
        gather_agg_kernel<<<gather_blocks, 256, 0, stream>>>(out, offsets, ssrc, agg, N);
        linear_kernel<<<linear_blocks, 256, 0, stream>>>(agg, out, W2_rel, b2, W2_root,
                                                         out, N, 0);
    } else {
        const int scatter_blocks = (int)(((long long)E * 24 + 255) / 256);
        hipMemsetAsync(agg, 0, aggB, stream);
        scatter_add_kernel<<<scatter_blocks, 256, 0, stream>>>(x, eidx, flag, agg, E, N);
        linear_kernel<<<linear_blocks, 256, 0, stream>>>(agg, x, W1_rel, b1, W1_root,
                                                         out, N, 1);
        hipMemsetAsync(agg, 0, aggB, stream);
        scatter_add_kernel<<<scatter_blocks, 256, 0, stream>>>(out, eidx, flag, agg, E, N);
        linear_kernel<<<linear_blocks, 256, 0, stream>>>(agg, out, W2_rel, b2, W2_root,
                                                         out, N, 0);
    }
}

// Round 4
// 343.624 us; speedup vs baseline: 7.0040x; 1.0741x over previous
//
#include <hip/hip_runtime.h>
#include <hip/hip_bf16.h>

#define DD 96

// ---------------- dtype detect ----------------
__global__ void detect_idx_kernel(const unsigned long long* __restrict__ idx,
                                  int* __restrict__ flag,
                                  unsigned long long nmax) {
    __shared__ int bad;
    if (threadIdx.x == 0) bad = 0;
    __syncthreads();
    unsigned long long v = idx[threadIdx.x];
    if (v >= nmax) bad = 1;
    __syncthreads();
    if (threadIdx.x == 0) *flag = bad ? 0 : 1;  // 1 => int64 layout
}

__device__ __forceinline__ int load_idx(const void* eidx, int isI64, int pos) {
    return isI64 ? (int)((const long long*)eidx)[pos] : ((const int*)eidx)[pos];
}

// ---------------- CSR build ----------------
// 4 edges per thread: 4 independent atomics in flight.
__global__ __launch_bounds__(256) void hist_kernel(
    const void* __restrict__ eidx, const int* __restrict__ flag,
    int* __restrict__ deg, int E, int n) {
    int e0 = (blockIdx.x * 256 + threadIdx.x) * 4;
    if (e0 >= E) return;
    const int isI64 = *flag;
    if (e0 + 4 <= E) {
        int d0 = load_idx(eidx, isI64, E + e0 + 0);
        int d1 = load_idx(eidx, isI64, E + e0 + 1);
        int d2 = load_idx(eidx, isI64, E + e0 + 2);
        int d3 = load_idx(eidx, isI64, E + e0 + 3);
        if ((unsigned)d0 < (unsigned)n) atomicAdd(&deg[d0], 1);
        if ((unsigned)d1 < (unsigned)n) atomicAdd(&deg[d1], 1);
        if ((unsigned)d2 < (unsigned)n) atomicAdd(&deg[d2], 1);
        if ((unsigned)d3 < (unsigned)n) atomicAdd(&deg[d3], 1);
    } else {
        for (int e = e0; e < E; ++e) {
            int d = load_idx(eidx, isI64, E + e);
            if ((unsigned)d < (unsigned)n) atomicAdd(&deg[d], 1);
        }
    }
}

#define SCAN_BLOCK 256
#define SCAN_ELEMS 1024

__global__ __launch_bounds__(SCAN_BLOCK) void scan1_kernel(
    const int* __restrict__ deg, int* __restrict__ partial,
    int* __restrict__ blockSums, int n) {
    __shared__ int sh[SCAN_BLOCK];
    int base = blockIdx.x * SCAN_ELEMS;
    int vals[4];
    int tsum = 0;
    #pragma unroll
    for (int u = 0; u < 4; ++u) {
        int idx = base + threadIdx.x * 4 + u;
        vals[u] = (idx < n) ? deg[idx] : 0;
        tsum += vals[u];
    }
    sh[threadIdx.x] = tsum;
    __syncthreads();
    int v = tsum;
    for (int off = 1; off < SCAN_BLOCK; off <<= 1) {
        int o = (threadIdx.x >= off) ? sh[threadIdx.x - off] : 0;
        __syncthreads();
        v += o;
        sh[threadIdx.x] = v;
        __syncthreads();
    }
    int run = v - tsum;
    #pragma unroll
    for (int u = 0; u < 4; ++u) {
        int idx = base + threadIdx.x * 4 + u;
        if (idx < n) partial[idx] = run;
        run += vals[u];
    }
    if (threadIdx.x == SCAN_BLOCK - 1) blockSums[blockIdx.x] = v;
}

__global__ __launch_bounds__(256) void scan2_kernel(int* __restrict__ blockSums, int nb) {
    __shared__ int sh[256];
    int v = (threadIdx.x < nb) ? blockSums[threadIdx.x] : 0;
    sh[threadIdx.x] = v;
    __syncthreads();
    int inc = v;
    for (int off = 1; off < 256; off <<= 1) {
        int o = (threadIdx.x >= off) ? sh[threadIdx.x - off] : 0;
        __syncthreads();
        inc += o;
        sh[threadIdx.x] = inc;
        __syncthreads();
    }
    if (threadIdx.x < nb) blockSums[threadIdx.x] = inc - v;
}

__global__ __launch_bounds__(256) void scan3_kernel(
    const int* __restrict__ partial, const int* __restrict__ blockSums,
    int* __restrict__ offsets, int* __restrict__ cursor, int n, int E) {
    int i = blockIdx.x * 256 + threadIdx.x;
    if (i < n) {
        int o = partial[i] + blockSums[i >> 10];
        offsets[i] = o;
        cursor[i] = o;
    }
    if (i == n) offsets[n] = E;
}

// 4 edges per thread: 4 independent cursor-atomics + 4 scattered stores.
__global__ __launch_bounds__(256) void bucket_kernel(
    const void* __restrict__ eidx, const int* __restrict__ flag,
    int* __restrict__ cursor, int* __restrict__ ssrc, int E, int n) {
    int e0 = (blockIdx.x * 256 + threadIdx.x) * 4;
    if (e0 >= E) return;
    const int isI64 = *flag;
    if (e0 + 4 <= E) {
        int s0 = load_idx(eidx, isI64, e0 + 0);
        int s1 = load_idx(eidx, isI64, e0 + 1);
        int s2 = load_idx(eidx, isI64, e0 + 2);
        int s3 = load_idx(eidx, isI64, e0 + 3);
        int d0 = load_idx(eidx, isI64, E + e0 + 0);
        int d1 = load_idx(eidx, isI64, E + e0 + 1);
        int d2 = load_idx(eidx, isI64, E + e0 + 2);
        int d3 = load_idx(eidx, isI64, E + e0 + 3);
        bool v0 = (unsigned)s0 < (unsigned)n && (unsigned)d0 < (unsigned)n;
        bool v1 = (unsigned)s1 < (unsigned)n && (unsigned)d1 < (unsigned)n;
        bool v2 = (unsigned)s2 < (unsigned)n && (unsigned)d2 < (unsigned)n;
        bool v3 = (unsigned)s3 < (unsigned)n && (unsigned)d3 < (unsigned)n;
        int p0 = v0 ? atomicAdd(&cursor[d0], 1) : 0;
        int p1 = v1 ? atomicAdd(&cursor[d1], 1) : 0;
        int p2 = v2 ? atomicAdd(&cursor[d2], 1) : 0;
        int p3 = v3 ? atomicAdd(&cursor[d3], 1) : 0;
        if (v0) ssrc[p0] = s0;
        if (v1) ssrc[p1] = s1;
        if (v2) ssrc[p2] = s2;
        if (v3) ssrc[p3] = s3;
    } else {
        for (int e = e0; e < E; ++e) {
            int s = load_idx(eidx, isI64, e);
            int d = load_idx(eidx, isI64, E + e);
            if ((unsigned)s >= (unsigned)n || (unsigned)d >= (unsigned)n) continue;
            int pos = atomicAdd(&cursor[d], 1);
            ssrc[pos] = s;
        }
    }
}

// ---------------- gather aggregation (no atomics) ----------------
// thread = (node i, float4-chunk c); edge loop unrolled x4, two accumulators
// -> 4 independent row loads in flight per thread.
__global__ __launch_bounds__(256) void gather_agg_kernel(
    const float* __restrict__ feat, const int* __restrict__ offsets,
    const int* __restrict__ ssrc, float* __restrict__ agg, int n) {
    long long t = (long long)blockIdx.x * 256 + threadIdx.x;
    if (t >= (long long)n * 24) return;
    int i = (int)(t / 24);
    int c = (int)(t % 24);
    int beg = offsets[i], end = offsets[i + 1];
    float4 accA = make_float4(0.f, 0.f, 0.f, 0.f);
    float4 accB = make_float4(0.f, 0.f, 0.f, 0.f);
    int j = beg;
    for (; j + 4 <= end; j += 4) {
        int s0 = ssrc[j + 0];
        int s1 = ssrc[j + 1];
        int s2 = ssrc[j + 2];
        int s3 = ssrc[j + 3];
        float4 v0 = ((const float4*)(feat + (size_t)s0 * DD))[c];
        float4 v1 = ((const float4*)(feat + (size_t)s1 * DD))[c];
        float4 v2 = ((const float4*)(feat + (size_t)s2 * DD))[c];
        float4 v3 = ((const float4*)(feat + (size_t)s3 * DD))[c];
        accA.x += v0.x; accA.y += v0.y; accA.z += v0.z; accA.w += v0.w;
        accB.x += v1.x; accB.y += v1.y; accB.z += v1.z; accB.w += v1.w;
        accA.x += v2.x; accA.y += v2.y; accA.z += v2.z; accA.w += v2.w;
        accB.x += v3.x; accB.y += v3.y; accB.z += v3.z; accB.w += v3.w;
    }
    for (; j < end; ++j) {
        int s = ssrc[j];
        float4 v = ((const float4*)(feat + (size_t)s * DD))[c];
        accA.x += v.x; accA.y += v.y; accA.z += v.z; accA.w += v.w;
    }
    accA.x += accB.x; accA.y += accB.y; accA.z += accB.z; accA.w += accB.w;
    ((float4*)(agg + (size_t)i * DD))[c] = accA;
}

// ---------------- fallback: atomic scatter ----------------
__global__ __launch_bounds__(256) void scatter_add_kernel(
    const float* __restrict__ feat, const void* __restrict__ eidx,
    const int* __restrict__ flag, float* __restrict__ agg,
    int E, int n) {
    long long t = (long long)blockIdx.x * 256 + threadIdx.x;
    if (t >= (long long)E * 24) return;
    int e = (int)(t / 24);
    int c = (int)(t % 24);
    int isI64 = *flag;
    int s = load_idx(eidx, isI64, e);
    int d = load_idx(eidx, isI64, E + e);
    if ((unsigned)s >= (unsigned)n || (unsigned)d >= (unsigned)n) return;
    const float4 v = ((const float4*)(feat + (size_t)s * DD))[c];
    float* o = agg + (size_t)d * DD + (size_t)c * 4;
    atomicAdd(o + 0, v.x);
    atomicAdd(o + 1, v.y);
    atomicAdd(o + 2, v.z);
    atomicAdd(o + 3, v.w);
}

// ---------------- fused dual-linear, LDS-staged weights ----------------
__global__ __launch_bounds__(256) void linear_kernel(
    const float* __restrict__ A, const float* __restrict__ X,
    const float* __restrict__ Wrel, const float* __restrict__ bias,
    const float* __restrict__ Wroot, float* __restrict__ out,
    int n, int do_relu) {
    __shared__ float wlds[DD * DD];  // 36864 B

    const int lane = threadIdx.x & 63;
    const int q = threadIdx.x >> 6;
    const int j0 = q * 24;
    const int m0 = blockIdx.x * 128 + lane;
    const int m1 = m0 + 64;
    const bool act0 = (m0 < n), act1 = (m1 < n);
    const int r0 = act0 ? m0 : 0;
    const int r1 = act1 ? m1 : 0;

    float acc0[24], acc1[24];
    {
        const float4* bq = (const float4*)(bias + j0);
        #pragma unroll
        for (int jj = 0; jj < 6; ++jj) {
            float4 b = bq[jj];
            acc0[jj*4+0] = b.x; acc0[jj*4+1] = b.y;
            acc0[jj*4+2] = b.z; acc0[jj*4+3] = b.w;
            acc1[jj*4+0] = b.x; acc1[jj*4+1] = b.y;
            acc1[jj*4+2] = b.z; acc1[jj*4+3] = b.w;
        }
    }

    const float* srcs[2] = {A, X};
    const float* mats[2] = {Wrel, Wroot};

    for (int phase = 0; phase < 2; ++phase) {
        {
            const float4* wg = (const float4*)mats[phase];
            float4* wl = (float4*)wlds;
            #pragma unroll
            for (int i = 0; i < 9; ++i)
                wl[threadIdx.x + i * 256] = wg[threadIdx.x + i * 256];
        }
        __syncthreads();

        const float* row0 = srcs[phase] + (size_t)r0 * DD;
        const float* row1 = srcs[phase] + (size_t)r1 * DD;

        for (int kk = 0; kk < DD; kk += 4) {
            float4 a0 = *(const float4*)(row0 + kk);
            float4 a1 = *(const float4*)(row1 + kk);
            const float av0[4] = {a0.x, a0.y, a0.z, a0.w};
            const float av1[4] = {a1.x, a1.y, a1.z, a1.w};
            #pragma unroll
            for (int u = 0; u < 4; ++u) {
                const float4* wrow = (const float4*)(&wlds[(kk + u) * DD + j0]);
                const float k0 = av0[u], k1 = av1[u];
                #pragma unroll
                for (int jj = 0; jj < 6; ++jj) {
                    float4 w = wrow[jj];
                    acc0[jj*4+0] = fmaf(k0, w.x, acc0[jj*4+0]);
                    acc0[jj*4+1] = fmaf(k0, w.y, acc0[jj*4+1]);
                    acc0[jj*4+2] = fmaf(k0, w.z, acc0[jj*4+2]);
                    acc0[jj*4+3] = fmaf(k0, w.w, acc0[jj*4+3]);
                    acc1[jj*4+0] = fmaf(k1, w.x, acc1[jj*4+0]);
                    acc1[jj*4+1] = fmaf(k1, w.y, acc1[jj*4+1]);
                    acc1[jj*4+2] = fmaf(k1, w.z, acc1[jj*4+2]);
                    acc1[jj*4+3] = fmaf(k1, w.w, acc1[jj*4+3]);
                }
            }
        }
        __syncthreads();
    }

    if (act0) {
        float4* o = (float4*)(out + (size_t)m0 * DD + j0);
        #pragma unroll
        for (int jj = 0; jj < 6; ++jj) {
            float4 v = make_float4(acc0[jj*4+0], acc0[jj*4+1],
                                   acc0[jj*4+2], acc0[jj*4+3]);
            if (do_relu) {
                v.x = fmaxf(v.x, 0.f); v.y = fmaxf(v.y, 0.f);
                v.z = fmaxf(v.z, 0.f); v.w = fmaxf(v.w, 0.f);
            }
            o[jj] = v;
        }
    }
    if (act1) {
        float4* o = (float4*)(out + (size_t)m1 * DD + j0);
        #pragma unroll
        for (int jj = 0; jj < 6; ++jj) {
            float4 v = make_float4(acc1[jj*4+0], acc1[jj*4+1],
                                   acc1[jj*4+2], acc1[jj*4+3]);
            if (do_relu) {
                v.x = fmaxf(v.x, 0.f); v.y = fmaxf(v.y, 0.f);
                v.z = fmaxf(v.z, 0.f); v.w = fmaxf(v.w, 0.f);
            }
            o[jj] = v;
        }
    }
}

extern "C" void kernel_launch(void* const* d_in, const int* in_sizes, int n_in,
                              void* d_out, int out_size, void* d_ws, size_t ws_size,
                              hipStream_t stream) {
    const float* x      = (const float*)d_in[0];
    const void*  eidx   = d_in[1];
    const float* W1_rel = (const float*)d_in[2];
    const float* b1     = (const float*)d_in[3];
    const float* W1_root= (const float*)d_in[4];
    const float* W2_rel = (const float*)d_in[5];
    const float* b2     = (const float*)d_in[6];
    const float* W2_root= (const float*)d_in[7];
    float* out = (float*)d_out;

    const int N = in_sizes[0] / DD;   // 50000
    const int E = in_sizes[1] / 2;    // 800000

    const size_t aggB = (size_t)N * DD * sizeof(float);
    char* base = (char*)d_ws;
    float* agg  = (float*)base;
    int*   flag = (int*)(base + aggB);
    size_t off = (aggB + 15) & ~(size_t)15;
    off += 16;
    int* offsets   = (int*)(base + off); off += (size_t)(N + 1) * 4;
    int* cursor    = (int*)(base + off); off += (size_t)N * 4;
    int* deg       = (int*)(base + off); off += (size_t)N * 4;
    int* partial   = (int*)(base + off); off += (size_t)N * 4;
    int* blockSums = (int*)(base + off); off += 256 * 4;
    int* ssrc      = (int*)(base + off); off += (size_t)E * 4;
    const bool csr_ok = (off <= ws_size) && (N <= SCAN_ELEMS * 256);

    const int linear_blocks = (N + 127) / 128;
    const int edge_blocks4 = (E + 1023) / 1024;

    detect_idx_kernel<<<1, 256, 0, stream>>>(
        (const unsigned long long*)eidx, flag, (unsigned long long)N);

    if (csr_ok) {
        const int NB = (N + SCAN_ELEMS - 1) / SCAN_ELEMS;
        const int gather_blocks = (int)(((long long)N * 24 + 255) / 256);

        hipMemsetAsync(deg, 0, (size_t)N * 4, stream);
        hist_kernel<<<edge_blocks4, 256, 0, stream>>>(eidx, flag, deg, E, N);
        scan1_kernel<<<NB, SCAN_BLOCK, 0, stream>>>(deg, partial, blockSums, N);
        scan2_kernel<<<1, 256, 0, stream>>>(blockSums, NB);
        scan3_kernel<<<(N + 256) / 256, 256, 0, stream>>>(partial, blockSums,
                                                          offsets, cursor, N, E);
        bucket_kernel<<<edge_blocks4, 256, 0, stream>>>(eidx, flag, cursor, ssrc, E, N);

        gather_agg_kernel<<<gather_blocks, 256, 0, stream>>>(x, offsets, ssrc, agg, N);
        linear_kernel<<<linear_blocks, 256, 0, stream>>>(agg, x, W1_rel, b1, W1_root,
                                                         out, N, 1);
        gather_agg_kernel<<<gather_blocks, 256, 0, stream>>>(out, offsets, ssrc, agg, N);
        linear_kernel<<<linear_blocks, 256, 0, stream>>>(agg, out, W2_rel, b2, W2_root,
                                                         out, N, 0);
    } else {
        const int scatter_blocks = (int)(((long long)E * 24 + 255) / 256);
        hipMemsetAsync(agg, 0, aggB, stream);
        scatter_add_kernel<<<scatter_blocks, 256, 0, stream>>>(x, eidx, flag, agg, E, N);
        linear_kernel<<<linear_blocks, 256, 0, stream>>>(agg, x, W1_rel, b1, W1_root,
                                                         out, N, 1);
        hipMemsetAsync(agg, 0, aggB, stream);
        scatter_add_kernel<<<scatter_blocks, 256, 0, stream>>>(out, eidx, flag, agg, E, N);
        linear_kernel<<<linear_blocks, 256, 0, stream>>>(agg, out, W2_rel, b2, W2_root,
                                                         out, N, 0);
    }
}